// Round 7
// baseline (1251.375 us; speedup 1.0000x reference)
//
#include <hip/hip_runtime.h>
#include <hip/hip_bf16.h>

#define TB 4
#define TN 640
#define TC 1024
#define TH 16
#define THD 64
#define TI 4096
#define TE 8
#define TT (TB*TN)     /* 2560 tokens */
#define TBH (TB*TH)    /* 64 */
#define SCALE_ 0.125f

typedef unsigned short u16;
typedef __bf16 bf16x8 __attribute__((ext_vector_type(8)));
typedef float f32x4 __attribute__((ext_vector_type(4)));

__device__ __forceinline__ float gelu_tanh(float v){
  float t = 0.7978845608f*(v + 0.044715f*v*v*v);
  // tanh(t) = 1 - 2/(exp(2t)+1)
  float e = __expf(2.f*t);
  float th = 1.f - 2.f/(e + 1.f);
  return 0.5f*v*(1.f + th);
}

// ---------------------------------------------------------------------------
// 8-wave (512-thread) bf16 MFMA GEMM, 2-phase STAGE-first pipeline, BK=64.
// Wave grid 2(M)x4(N); per-wave tile (BM/2)x(BN/4). XOR-8 source+read swizzle
// (conflict-free, verified r3-r6). One __syncthreads per K-step; per-step MFMA
// (~2048 CU-cyc at 256x256) covers the load latency before the barrier drain.
// EPI: 1=store bf16 (row aoff+i), 3=gelu->bf16 (row aoff+i)
// ---------------------------------------------------------------------------
template<int BM, int BN, bool GATHER, int EPI>
__global__ __launch_bounds__(512) void gemm_big(
    const u16* __restrict__ A, const u16* __restrict__ Wb, void* __restrict__ Cout,
    const float* __restrict__ bias, long biasStride,
    const int* __restrict__ idxList, long idxStride,
    const int* __restrict__ counts, const int* __restrict__ offsets,
    int M, int Kfull, int nby, int ldc, long sA, long sW)
{
  constexpr int FM = BM/32, FN = BN/64;
  constexpr int AI = BM/64, BI = BN/64;

  const int ze = blockIdx.z;

  const int nwg = gridDim.x;
  int lin = blockIdx.x;
  int q = nwg >> 3, r = nwg & 7;
  int xcd = lin & 7, pos = lin >> 3;
  int swz = (xcd < r ? xcd*(q+1) : r*(q+1) + (xcd-r)*q) + pos;
  const int bx = swz / nby;
  const int by = swz - bx*nby;

  int mcount = M, aoff = 0;
  if (counts){ mcount = counts[ze]; aoff = offsets ? offsets[ze] : 0; }
  if (by*BM >= mcount) return;

  const int tid = threadIdx.x, w = tid>>6, lane = tid&63;
  const int wm = w>>2, wn = w&3;

  __shared__ __align__(16) u16 As[2][BM*64];
  __shared__ __align__(16) u16 Bs[2][BN*64];

  const u16* Az = A + (long)ze*sA;
  const u16* Wz = Wb + (long)ze*sW;
  const int* idx_z = idxList ? (idxList + (long)ze*idxStride) : nullptr;

  const int c16 = (lane&7) ^ ((lane>>3)&7);
  long a_src[AI];
  #pragma unroll
  for (int j=0;j<AI;j++){
    int i = by*BM + (w*AI+j)*8 + (lane>>3);
    int row;
    if (counts){
      int ie = (i < mcount) ? i : (mcount-1);
      row = GATHER ? idx_z[ie] : (aoff + ie);
    } else row = i;
    a_src[j] = (long)row*Kfull + c16*8;
  }
  long b_src[BI];
  #pragma unroll
  for (int j=0;j<BI;j++){
    int rr = bx*BN + (w*BI+j)*8 + (lane>>3);
    b_src[j] = (long)rr*Kfull + c16*8;
  }

  auto STAGE = [&](int buf, int t){
    #pragma unroll
    for (int j=0;j<AI;j++)
      __builtin_amdgcn_global_load_lds(
        (const __attribute__((address_space(1))) void*)(Az + a_src[j] + t*64),
        (__attribute__((address_space(3))) void*)(&As[buf][(w*AI+j)*512]), 16, 0, 0);
    #pragma unroll
    for (int j=0;j<BI;j++)
      __builtin_amdgcn_global_load_lds(
        (const __attribute__((address_space(1))) void*)(Wz + b_src[j] + t*64),
        (__attribute__((address_space(3))) void*)(&Bs[buf][(w*BI+j)*512]), 16, 0, 0);
  };

  f32x4 acc[FM][FN];
  #pragma unroll
  for (int m=0;m<FM;m++)
    #pragma unroll
    for (int n=0;n<FN;n++) acc[m][n] = (f32x4){0.f,0.f,0.f,0.f};

  const int nt = Kfull >> 6;
  STAGE(0, 0);
  __syncthreads();
  int cur = 0;
  const int lr = lane & 15;
  const int s0 = (lane>>4) ^ (lane&7);
  const int abase = lr*128 + s0*16;

  for (int t=0; t<nt; ++t){
    if (t+1 < nt) STAGE(cur^1, t+1);
    const char* Ab = (const char*)&As[cur][0];
    const char* Bb = (const char*)&Bs[cur][0];
    bf16x8 af[FM][2], bfr[FN][2];
    #pragma unroll
    for (int m=0;m<FM;m++){
      af[m][0] = *reinterpret_cast<const bf16x8*>(Ab + wm*(BM/2)*128 + m*2048 + abase);
      af[m][1] = *reinterpret_cast<const bf16x8*>(Ab + wm*(BM/2)*128 + m*2048 + (abase^64));
    }
    #pragma unroll
    for (int n=0;n<FN;n++){
      bfr[n][0] = *reinterpret_cast<const bf16x8*>(Bb + wn*(BN/4)*128 + n*2048 + abase);
      bfr[n][1] = *reinterpret_cast<const bf16x8*>(Bb + wn*(BN/4)*128 + n*2048 + (abase^64));
    }
    #pragma unroll
    for (int m=0;m<FM;m++)
      #pragma unroll
      for (int n=0;n<FN;n++){
        acc[m][n] = __builtin_amdgcn_mfma_f32_16x16x32_bf16(af[m][0], bfr[n][0], acc[m][n], 0,0,0);
        acc[m][n] = __builtin_amdgcn_mfma_f32_16x16x32_bf16(af[m][1], bfr[n][1], acc[m][n], 0,0,0);
      }
    __syncthreads();
    cur ^= 1;
  }

  const float* bz = bias ? (bias + (long)ze*biasStride) : nullptr;
  #pragma unroll
  for (int m=0;m<FM;m++){
    #pragma unroll
    for (int n=0;n<FN;n++){
      int gcol = bx*BN + wn*(BN/4) + n*16 + (lane&15);
      float bv = bz ? bz[gcol] : 0.f;
      #pragma unroll
      for (int jj=0;jj<4;jj++){
        int i = by*BM + wm*(BM/2) + m*16 + (lane>>4)*4 + jj;
        if (counts && i >= mcount) continue;
        float v = acc[m][n][jj] + bv;
        if constexpr (EPI == 1){
          ((__hip_bfloat16*)Cout)[(long)(aoff+i)*ldc + gcol] = __float2bfloat16(v);
        } else { // EPI == 3
          ((__hip_bfloat16*)Cout)[(long)(aoff+i)*ldc + gcol] = __float2bfloat16(gelu_tanh(v));
        }
      }
    }
  }
}

// ---------------------------------------------------------------------------
// 4-wave 128-class GEMM (kept for proj/scores/PV).
// EPI: 0=store f32, 1=store bf16, 2=resadd x += v*scalevec (non-atomic RMW)
// ---------------------------------------------------------------------------
template<int BM, int BN, int EPI>
__global__ __launch_bounds__(256) void gemm_bt(
    const u16* __restrict__ A, const u16* __restrict__ Wb, void* __restrict__ Cout,
    const float* __restrict__ bias, const float* __restrict__ scalevec,
    int M, int Kfull, int nby, int ldc,
    long sA, long sW, long sCo, long sCi, int Z2)
{
  constexpr int FM = BM/32, FN = BN/32;
  constexpr int AI = BM/32, BI = BN/32;

  const int ze = blockIdx.z;
  const int nwg = gridDim.x;
  int lin = blockIdx.x;
  int q = nwg >> 3, r = nwg & 7;
  int xcd = lin & 7, pos = lin >> 3;
  int swz = (xcd < r ? xcd*(q+1) : r*(q+1) + (xcd-r)*q) + pos;
  const int bx = swz / nby;
  const int by = swz - bx*nby;
  if (by*BM >= M) return;

  const int tid = threadIdx.x, w = tid>>6, lane = tid&63;
  const int wm = w>>1, wn = w&1;

  __shared__ __align__(16) u16 As[2][BM*64];
  __shared__ __align__(16) u16 Bs[2][BN*64];

  const u16* Az = A + (long)ze*sA;
  const u16* Wz = Wb + (long)ze*sW;

  const int c16 = (lane&7) ^ ((lane>>3)&7);
  long a_src[AI];
  #pragma unroll
  for (int j=0;j<AI;j++){
    int i = by*BM + (w*AI+j)*8 + (lane>>3);
    a_src[j] = (long)i*Kfull + c16*8;
  }
  long b_src[BI];
  #pragma unroll
  for (int j=0;j<BI;j++){
    int rr = bx*BN + (w*BI+j)*8 + (lane>>3);
    b_src[j] = (long)rr*Kfull + c16*8;
  }

  auto STAGE = [&](int buf, int t){
    #pragma unroll
    for (int j=0;j<AI;j++)
      __builtin_amdgcn_global_load_lds(
        (const __attribute__((address_space(1))) void*)(Az + a_src[j] + t*64),
        (__attribute__((address_space(3))) void*)(&As[buf][(w*AI+j)*512]), 16, 0, 0);
    #pragma unroll
    for (int j=0;j<BI;j++)
      __builtin_amdgcn_global_load_lds(
        (const __attribute__((address_space(1))) void*)(Wz + b_src[j] + t*64),
        (__attribute__((address_space(3))) void*)(&Bs[buf][(w*BI+j)*512]), 16, 0, 0);
  };

  f32x4 acc[FM][FN];
  #pragma unroll
  for (int m=0;m<FM;m++)
    #pragma unroll
    for (int n=0;n<FN;n++) acc[m][n] = (f32x4){0.f,0.f,0.f,0.f};

  const int nt = Kfull >> 6;
  STAGE(0, 0);
  __syncthreads();
  int cur = 0;
  const int lr = lane & 15;
  const int s0 = (lane>>4) ^ (lane&7);
  const int abase = lr*128 + s0*16;

  for (int t=0; t<nt; ++t){
    if (t+1 < nt) STAGE(cur^1, t+1);
    const char* Ab = (const char*)&As[cur][0];
    const char* Bb = (const char*)&Bs[cur][0];
    bf16x8 af[FM][2], bfr[FN][2];
    #pragma unroll
    for (int m=0;m<FM;m++){
      af[m][0] = *reinterpret_cast<const bf16x8*>(Ab + wm*(BM/2)*128 + m*2048 + abase);
      af[m][1] = *reinterpret_cast<const bf16x8*>(Ab + wm*(BM/2)*128 + m*2048 + (abase^64));
    }
    #pragma unroll
    for (int n=0;n<FN;n++){
      bfr[n][0] = *reinterpret_cast<const bf16x8*>(Bb + wn*(BN/2)*128 + n*2048 + abase);
      bfr[n][1] = *reinterpret_cast<const bf16x8*>(Bb + wn*(BN/2)*128 + n*2048 + (abase^64));
    }
    #pragma unroll
    for (int m=0;m<FM;m++)
      #pragma unroll
      for (int n=0;n<FN;n++){
        acc[m][n] = __builtin_amdgcn_mfma_f32_16x16x32_bf16(af[m][0], bfr[n][0], acc[m][n], 0,0,0);
        acc[m][n] = __builtin_amdgcn_mfma_f32_16x16x32_bf16(af[m][1], bfr[n][1], acc[m][n], 0,0,0);
      }
    __syncthreads();
    cur ^= 1;
  }

  long csel = (long)(ze/Z2)*sCo + (long)(ze%Z2)*sCi;
  #pragma unroll
  for (int m=0;m<FM;m++){
    #pragma unroll
    for (int n=0;n<FN;n++){
      int gcol = bx*BN + wn*(BN/2) + n*16 + (lane&15);
      float bv = bias ? bias[gcol] : 0.f;
      #pragma unroll
      for (int jj=0;jj<4;jj++){
        int i = by*BM + wm*(BM/2) + m*16 + (lane>>4)*4 + jj;
        float v = acc[m][n][jj] + bv;
        if constexpr (EPI == 0){
          ((float*)Cout)[csel + (long)i*ldc + gcol] = v;
        } else if constexpr (EPI == 1){
          ((__hip_bfloat16*)Cout)[csel + (long)i*ldc + gcol] = __float2bfloat16(v);
        } else {
          float* p = (float*)Cout + csel + (long)i*ldc + gcol;
          *p += v * scalevec[gcol];
        }
      }
    }
  }
}

// ---------------------------------------------------------------------------
__global__ __launch_bounds__(256) void cvt_kernel(const float* __restrict__ s,
    u16* __restrict__ d, long n)
{
  long i = ((long)blockIdx.x*256 + threadIdx.x)*8;
  if (i >= n) return;
  float4 a = *(const float4*)(s+i);
  float4 b = *(const float4*)(s+i+4);
  union { __hip_bfloat162 h[4]; uint4 v; } o;
  o.h[0] = __float22bfloat162_rn(make_float2(a.x,a.y));
  o.h[1] = __float22bfloat162_rn(make_float2(a.z,a.w));
  o.h[2] = __float22bfloat162_rn(make_float2(b.x,b.y));
  o.h[3] = __float22bfloat162_rn(make_float2(b.z,b.w));
  *(uint4*)(d+i) = o.v;
}

__global__ __launch_bounds__(256) void init_x_kernel(const float* __restrict__ h,
    float* __restrict__ x, int n)
{
  int i = blockIdx.x*256 + threadIdx.x;
  if (i < n) x[i] = h[i];
  else if (i == n) x[i] = 0.f;   // aux slot
}

__global__ __launch_bounds__(256) void ln_kernel(const float* __restrict__ x,
    const float* __restrict__ s, const float* __restrict__ b,
    float* __restrict__ of, __hip_bfloat16* __restrict__ ob)
{
  int row = blockIdx.x, tid = threadIdx.x;
  const float* xr = x + (long)row*TC;
  int c = tid*4;
  float4 xv = *(const float4*)(xr + c);
  float sum = xv.x+xv.y+xv.z+xv.w;
  float sq = xv.x*xv.x+xv.y*xv.y+xv.z*xv.z+xv.w*xv.w;
  #pragma unroll
  for (int o=32;o;o>>=1){ sum += __shfl_down(sum,o); sq += __shfl_down(sq,o); }
  __shared__ float ls[8];
  if ((tid&63)==0){ ls[tid>>6] = sum; ls[4+(tid>>6)] = sq; }
  __syncthreads();
  float mean = (ls[0]+ls[1]+ls[2]+ls[3]) * (1.f/TC);
  float ex2  = (ls[4]+ls[5]+ls[6]+ls[7]) * (1.f/TC);
  float rstd = rsqrtf(ex2 - mean*mean + 1e-6f);
  float4 sv = *(const float4*)(s + c);
  float4 bv = *(const float4*)(b + c);
  float o0 = (xv.x-mean)*rstd*sv.x + bv.x;
  float o1 = (xv.y-mean)*rstd*sv.y + bv.y;
  float o2 = (xv.z-mean)*rstd*sv.z + bv.z;
  float o3 = (xv.w-mean)*rstd*sv.w + bv.w;
  *(float4*)(of + (long)row*TC + c) = make_float4(o0,o1,o2,o3);
  __hip_bfloat16* op = ob + (long)row*TC + c;
  *reinterpret_cast<__hip_bfloat162*>(op)   = __float22bfloat162_rn(make_float2(o0,o1));
  *reinterpret_cast<__hip_bfloat162*>(op+2) = __float22bfloat162_rn(make_float2(o2,o3));
}

__global__ void build_qkv_bias(const float* __restrict__ qb, const float* __restrict__ vb,
    float* __restrict__ out)
{
  int i = blockIdx.x*256 + threadIdx.x;
  if (i >= 3*TC) return;
  float v = 0.f;
  if (i < TC) v = qb[i];
  else if (i >= 2*TC) v = vb[i-2*TC];
  out[i] = v;
}

// grid (TN/128, TBH): copy q,k sections; LDS-transpose v into vT[bh][d][n]
__global__ __launch_bounds__(256) void qkv_reshape(const u16* __restrict__ qkv,
    u16* __restrict__ q, u16* __restrict__ k, u16* __restrict__ vT)
{
  const int bh = blockIdx.y, b = bh>>4, h = bh&15;
  const int n0 = blockIdx.x*128;
  const int tid = threadIdx.x;
  const long rowbase = ((long)b*TN + n0)*(3*TC) + h*THD;
  __shared__ u16 vt[128][72];
  #pragma unroll
  for (int j=0;j<4;j++){
    int f = j*2048 + tid*8;
    int r = f>>6, d = f&63;
    long src = rowbase + (long)r*(3*TC) + d;
    long dst = ((long)bh*TN + n0 + r)*THD + d;
    *(uint4*)(q + dst) = *(const uint4*)(qkv + src);
    *(uint4*)(k + dst) = *(const uint4*)(qkv + src + TC);
    *(uint4*)(&vt[r][d]) = *(const uint4*)(qkv + src + 2*TC);
  }
  __syncthreads();
  #pragma unroll
  for (int j=0;j<4;j++){
    int f = j*2048 + tid*8;
    int dr = f>>7, nc = f&127;
    union { uint4 v; u16 u[8]; } o;
    #pragma unroll
    for (int e=0;e<8;e++) o.u[e] = vt[nc+e][dr];
    *(uint4*)(vT + ((long)bh*THD + dr)*TN + n0 + nc) = o.v;
  }
}

__global__ __launch_bounds__(256) void softmax_kernel(const float* __restrict__ S,
    const float* __restrict__ rpb, const int* __restrict__ mask, __hip_bfloat16* __restrict__ P)
{
  int row = blockIdx.x, tid = threadIdx.x;
  int qpos = row % TN;
  int bh = row / TN;
  int h = bh & (TH-1);
  int b = bh >> 4;
  const float* srow = S + (long)row*TN;
  const float* rrow = rpb + ((long)h*TN + qpos)*TN;
  const int* mrow = mask + b*TN;
  float v[3];
  float mx = -3e38f;
  #pragma unroll
  for (int j=0;j<3;j++){
    int kk = tid + j*256;
    float t = -3e38f;
    if (kk < TN){
      t = srow[kk]*SCALE_ + rrow[kk];
      if (mrow[kk] == 0) t = -1e30f;
    }
    v[j] = t;
    mx = fmaxf(mx, t);
  }
  #pragma unroll
  for (int o=32;o;o>>=1) mx = fmaxf(mx, __shfl_down(mx,o));
  __shared__ float ls[4], ls2[4];
  if ((tid&63)==0) ls[tid>>6] = mx;
  __syncthreads();
  mx = fmaxf(fmaxf(ls[0],ls[1]), fmaxf(ls[2],ls[3]));
  float sum = 0.f;
  #pragma unroll
  for (int j=0;j<3;j++){
    int kk = tid + j*256;
    if (kk < TN){ v[j] = __expf(v[j]-mx); sum += v[j]; }
  }
  #pragma unroll
  for (int o=32;o;o>>=1) sum += __shfl_down(sum,o);
  if ((tid&63)==0) ls2[tid>>6] = sum;
  __syncthreads();
  float inv = 1.f/(ls2[0]+ls2[1]+ls2[2]+ls2[3]);
  #pragma unroll
  for (int j=0;j<3;j++){
    int kk = tid + j*256;
    if (kk < TN) P[(long)row*TN + kk] = __float2bfloat16(v[j]*inv);
  }
}

__global__ __launch_bounds__(256) void gate_kernel(const float* __restrict__ ln,
    const float* __restrict__ gw, float* __restrict__ logits)
{
  int t = blockIdx.x, tid = threadIdx.x;
  int c = tid*4;
  float4 xv = *(const float4*)(ln + (long)t*TC + c);
  __shared__ float ls[4];
  for (int e=0;e<TE;e++){
    float4 wv = *(const float4*)(gw + (long)e*TC + c);
    float p = xv.x*wv.x + xv.y*wv.y + xv.z*wv.z + xv.w*wv.w;
    #pragma unroll
    for (int o=32;o;o>>=1) p += __shfl_down(p,o);
    if ((tid&63)==0) ls[tid>>6] = p;
    __syncthreads();
    if (tid==0) logits[(long)t*TE + e] = ls[0]+ls[1]+ls[2]+ls[3];
    __syncthreads();
  }
}

__global__ __launch_bounds__(256) void routing_kernel(const float* __restrict__ logits,
    int* __restrict__ counts, int* __restrict__ etok,
    int* __restrict__ tE, int* __restrict__ tP, float* __restrict__ tG,
    float* __restrict__ psum)
{
  __shared__ float ps[TE];
  int tid = threadIdx.x;
  if (tid < TE) ps[tid] = 0.f;
  __syncthreads();
  int t = blockIdx.x*256 + tid;
  if (t < TT){
    float pr[TE]; float mx = -3e38f;
    #pragma unroll
    for (int e=0;e<TE;e++){ pr[e] = logits[(long)t*TE+e]; mx = fmaxf(mx, pr[e]); }
    float sum = 0.f;
    #pragma unroll
    for (int e=0;e<TE;e++){ pr[e] = __expf(pr[e]-mx); sum += pr[e]; }
    float inv = 1.f/sum;
    #pragma unroll
    for (int e=0;e<TE;e++) pr[e] *= inv;
    int i1 = 0;
    #pragma unroll
    for (int e=1;e<TE;e++) if (pr[e] > pr[i1]) i1 = e;
    int i2 = -1;
    #pragma unroll
    for (int e=0;e<TE;e++){ if (e==i1) continue; if (i2<0 || pr[e]>pr[i2]) i2=e; }
    float p1 = pr[i1], p2 = pr[i2];
    float g1 = p1/(p1+p2), g2 = p2/(p1+p2);
    int pos1 = atomicAdd(&counts[i1], 1);
    etok[i1*TT + pos1] = t;
    int pos2 = atomicAdd(&counts[i2], 1);
    etok[i2*TT + pos2] = t;
    tE[2*t] = i1; tP[2*t] = pos1; tG[2*t] = g1;
    tE[2*t+1] = i2; tP[2*t+1] = pos2; tG[2*t+1] = g2;
    #pragma unroll
    for (int e=0;e<TE;e++) atomicAdd(&ps[e], pr[e]);
  }
  __syncthreads();
  if (tid < TE) atomicAdd(&psum[tid], ps[tid]);
}

__global__ void finalize_routing(const int* __restrict__ counts, int* __restrict__ offsets,
    const float* __restrict__ psum, float* __restrict__ aux)
{
  int off = 0; float a = 0.f;
  for (int e=0;e<TE;e++){
    offsets[e] = off; off += counts[e];
    a += (psum[e]*(1.f/TT)) * ((float)counts[e]*(1.f/TT));
  }
  aux[0] += (float)TE * a;
}

// x[t] += (g1*y[slot1] + g2*y[slot2]) * gamma2   (grid TT, 256 thr, 4 col/thr)
__global__ __launch_bounds__(256) void combine_kernel(
    const u16* __restrict__ y, const int* __restrict__ tE, const int* __restrict__ tP,
    const float* __restrict__ tG, const int* __restrict__ offsets,
    const float* __restrict__ gamma2, float* __restrict__ x)
{
  int t = blockIdx.x, c = threadIdx.x*4;
  int e1 = tE[2*t], e2 = tE[2*t+1];
  long s1 = (long)(offsets[e1]+tP[2*t])*TC + c;
  long s2 = (long)(offsets[e2]+tP[2*t+1])*TC + c;
  float g1 = tG[2*t], g2 = tG[2*t+1];
  ushort4 y1 = *(const ushort4*)(y+s1);
  ushort4 y2 = *(const ushort4*)(y+s2);
  float4 gv = *(const float4*)(gamma2 + c);
  float* xp = x + (long)t*TC + c;
  float4 xv = *(const float4*)xp;
  auto b2f = [](u16 u){ union{float f;unsigned i;} v; v.i = (unsigned)u<<16; return v.f; };
  xv.x += (g1*b2f(y1.x) + g2*b2f(y2.x))*gv.x;
  xv.y += (g1*b2f(y1.y) + g2*b2f(y2.y))*gv.y;
  xv.z += (g1*b2f(y1.z) + g2*b2f(y2.z))*gv.z;
  xv.w += (g1*b2f(y1.w) + g2*b2f(y2.w))*gv.w;
  *(float4*)xp = xv;
}

// ---------------------------------------------------------------------------
extern "C" void kernel_launch(void* const* d_in, const int* in_sizes, int n_in,
                              void* d_out, int out_size, void* d_ws, size_t ws_size,
                              hipStream_t stream) {
  (void)in_sizes; (void)n_in; (void)out_size; (void)ws_size;
  const float* hidden = (const float*)d_in[0];
  const int*   amask  = (const int*)d_in[1];
  const float* rpb    = (const float*)d_in[2];
  const float* qkv_w  = (const float*)d_in[3];
  const float* q_bias = (const float*)d_in[4];
  const float* v_bias = (const float*)d_in[5];
  const float* proj_w = (const float*)d_in[6];
  const float* proj_b = (const float*)d_in[7];
  const float* ln1_s  = (const float*)d_in[8];
  const float* ln1_b  = (const float*)d_in[9];
  const float* ln2_s  = (const float*)d_in[10];
  const float* ln2_b  = (const float*)d_in[11];
  const float* gamma1 = (const float*)d_in[12];
  const float* gamma2 = (const float*)d_in[13];
  const float* gate_w = (const float*)d_in[14];
  const float* fc1_w  = (const float*)d_in[15];
  const float* fc1_b  = (const float*)d_in[16];
  const float* fc2_w  = (const float*)d_in[17];
  const float* fc2_b  = (const float*)d_in[18];

  float* x = (float*)d_out;
  const int NXC = TT*TC;

  char* p = (char*)d_ws;
  auto alloc = [&](size_t bytes)->void* {
    void* r = (void*)p; p += (bytes + 255) & ~(size_t)255; return r;
  };
  float* qkvbias = (float*)alloc(3*TC*4);
  u16*   ln_bf   = (u16*)alloc((size_t)TT*TC*2);
  float* ln_f    = (float*)alloc((size_t)TT*TC*4);
  float* logits  = (float*)alloc((size_t)TT*TE*4);
  int*   counts  = (int*)alloc(TE*4);
  int*   offsets = (int*)alloc(TE*4);
  float* psum    = (float*)alloc(TE*4);
  int*   etok    = (int*)alloc((size_t)TE*TT*4);
  int*   tE      = (int*)alloc((size_t)2*TT*4);
  int*   tP      = (int*)alloc((size_t)2*TT*4);
  float* tG      = (float*)alloc((size_t)2*TT*4);
  char* arena = (char*)alloc(202375168);
  // attention phase
  float* scores  = (float*)(arena);                         // 104,857,600
  u16*   Pb      = (u16*)(arena + 104857600);               //  52,428,800
  u16*   qkv_bf  = (u16*)(arena + 157286400);               //  15,728,640
  u16*   qb      = (u16*)(arena + 173015040);               //   5,242,880
  u16*   kb      = (u16*)(arena + 178257920);               //   5,242,880
  u16*   vT      = (u16*)(arena + 183500800);               //   5,242,880
  u16*   attn_o  = (u16*)(arena + 188743680);               //   5,242,880
  u16*   wqkv    = (u16*)(arena + 193986560);               //   6,291,456
  u16*   wproj   = (u16*)(arena + 200278016);               //   2,097,152
  // MoE phase (overlays attention-phase buffers — dead by then)
  u16*   fc1b    = (u16*)(arena);                           //  67,108,864
  u16*   fc2b    = (u16*)(arena + 67108864);                //  67,108,864
  u16*   h1      = (u16*)(arena + 134217728);               //  41,943,040 (2*TT x TI bf16)
  u16*   yslot   = (u16*)(arena + 176160768);               //  10,485,760 (2*TT x TC bf16)

  init_x_kernel<<<(NXC+1+255)/256, 256, 0, stream>>>(hidden, x, NXC);

  for (int l=0;l<2;l++){
    // --- attention ---
    ln_kernel<<<TT, 256, 0, stream>>>(x, ln1_s + l*TC, ln1_b + l*TC, ln_f, (__hip_bfloat16*)ln_bf);
    build_qkv_bias<<<(3*TC+255)/256, 256, 0, stream>>>(q_bias + l*TC, v_bias + l*TC, qkvbias);
    cvt_kernel<<<(3*TC*TC)/2048, 256, 0, stream>>>(qkv_w + (size_t)l*3*TC*TC, wqkv, (long)3*TC*TC);
    cvt_kernel<<<(TC*TC)/2048, 256, 0, stream>>>(proj_w + (size_t)l*TC*TC, wproj, (long)TC*TC);
    gemm_big<128,256,false,1><<<dim3(12*20,1,1), 512, 0, stream>>>(
        ln_bf, wqkv, qkv_bf, qkvbias, 0, nullptr, 0, nullptr, nullptr,
        TT, TC, 20, 3*TC, 0, 0);
    qkv_reshape<<<dim3(TN/128, TBH), 256, 0, stream>>>(qkv_bf, qb, kb, vT);
    gemm_bt<128,128,0><<<dim3(5*5,1,TBH), 256, 0, stream>>>(
        qb, kb, scores, nullptr, nullptr,
        TN, THD, 5, TN, (long)TN*THD, (long)TN*THD, (long)TN*TN, 0, 1);
    softmax_kernel<<<TBH*TN, 256, 0, stream>>>(scores, rpb, amask, (__hip_bfloat16*)Pb);
    cvt_kernel<<<(TE*TI*TC)/2048, 256, 0, stream>>>(fc1_w + (size_t)l*TE*TI*TC, fc1b, (long)TE*TI*TC);
    gemm_bt<128,64,1><<<dim3(1*5,1,TBH), 256, 0, stream>>>(
        Pb, vT, attn_o, nullptr, nullptr,
        TN, TN, 5, TC, (long)TN*TN, (long)THD*TN, (long)TN*TC, THD, TH);
    cvt_kernel<<<(TE*TC*TI)/2048, 256, 0, stream>>>(fc2_w + (size_t)l*TE*TC*TI, fc2b, (long)TE*TC*TI);
    gemm_bt<64,128,2><<<dim3(8*40,1,1), 256, 0, stream>>>(
        attn_o, wproj, x, proj_b + l*TC, gamma1 + l*TC,
        TT, TC, 40, TC, 0,0,0,0,1);

    // --- MoE ---
    ln_kernel<<<TT, 256, 0, stream>>>(x, ln2_s + l*TC, ln2_b + l*TC, ln_f, (__hip_bfloat16*)ln_bf);
    gate_kernel<<<TT, 256, 0, stream>>>(ln_f, gate_w + (size_t)l*TE*TC, logits);
    hipMemsetAsync(counts, 0, TE*4, stream);
    hipMemsetAsync(psum, 0, TE*4, stream);
    routing_kernel<<<(TT+255)/256, 256, 0, stream>>>(logits, counts, etok, tE, tP, tG, psum);
    finalize_routing<<<1, 1, 0, stream>>>(counts, offsets, psum, x + NXC);
    gemm_big<256,256,true,3><<<dim3(16*10,1,TE), 512, 0, stream>>>(
        ln_bf, fc1b, h1, fc1_b + (size_t)l*TE*TI, TI, etok, TT, counts, offsets,
        TT, TC, 10, TI, 0, (long)TI*TC);
    gemm_big<128,256,false,1><<<dim3(4*20,1,TE), 512, 0, stream>>>(
        h1, fc2b, yslot, fc2_b + (size_t)l*TE*TC, TC, nullptr, 0, counts, offsets,
        TT, TI, 20, TC, 0, (long)TC*TI);
    combine_kernel<<<TT, 256, 0, stream>>>(yslot, tE, tP, tG, offsets, gamma2 + l*TC, x);
  }
}

// Round 8
// 1111.187 us; speedup vs baseline: 1.1262x; 1.1262x over previous
//
#include <hip/hip_runtime.h>
#include <hip/hip_bf16.h>

#define TB 4
#define TN 640
#define TC 1024
#define TH 16
#define THD 64
#define TI 4096
#define TE 8
#define TT (TB*TN)     /* 2560 tokens */
#define TBH (TB*TH)    /* 64 */
#define SCALE_ 0.125f
#define NT1 32         /* cap: 256-row tiles across experts */
#define NT2 48         /* cap: 128-row tiles across experts */

typedef unsigned short u16;
typedef __bf16 bf16x8 __attribute__((ext_vector_type(8)));
typedef float f32x4 __attribute__((ext_vector_type(4)));

__device__ __forceinline__ float gelu_tanh(float v){
  float t = 0.7978845608f*(v + 0.044715f*v*v*v);
  float e = __expf(2.f*t);
  return 0.5f*v*(1.f + (1.f - 2.f/(e + 1.f)));
}

// ---------------------------------------------------------------------------
// 8-wave bf16 GEMM, 2-phase pipeline with STATICALLY-NAMED double buffers
// (compile-time-disjoint LDS: no aliasing-forced vmcnt(0) before ds_read).
// MODE 0: plain rows.  MODE 1: tile-mapped + gather via etok (fc1).
// MODE 2: tile-mapped, compact rows (fc2).   EPI 1: bf16 (+bias if kc==0);
// EPI 3: gelu->bf16 (+bias).
// ---------------------------------------------------------------------------
template<int BM,int BN,int MODE,int EPI>
__global__ __launch_bounds__(512) void gemm8(
    const u16* __restrict__ A, const u16* __restrict__ Wb, void* __restrict__ Cout,
    const float* __restrict__ bias, long biasStride,
    const int* __restrict__ tE, const int* __restrict__ tL,
    const int* __restrict__ tC, const int* __restrict__ tO,
    const int* __restrict__ etok,
    int M, int Kfull, int Kchunk, int n0, int ldc, long sW, long sCk)
{
  constexpr int FM = BM/32, FN = BN/64;
  constexpr int AI = BM/64, BI = BN/64;

  const int nwg = gridDim.x;
  int lin = blockIdx.x;
  int q = nwg >> 3, r = nwg & 7;
  int xcd = lin & 7, pos = lin >> 3;
  int swz = (xcd < r ? xcd*(q+1) : r*(q+1) + (xcd-r)*q) + pos;
  const int id0 = swz % n0, id1 = swz / n0;

  int e, loc0, cnt, off0, bx;
  if constexpr (MODE == 0){
    e = 0; loc0 = id0*BM; cnt = M; off0 = 0; bx = id1;
  } else {
    bx = id0;
    e = tE[id1]; if (e < 0) return;
    loc0 = tL[id1]; cnt = tC[id1]; off0 = tO[id1];
  }
  const int kc = blockIdx.z;
  const long kbase = (long)kc * Kchunk;

  const int tid = threadIdx.x, w = tid>>6, lane = tid&63;
  const int wm = w>>2, wn = w&3;

  __shared__ __align__(16) u16 As0[BM*64], As1[BM*64];
  __shared__ __align__(16) u16 Bs0[BN*64], Bs1[BN*64];

  const u16* Wz = Wb + (long)e*sW;

  const int c16 = (lane&7) ^ ((lane>>3)&7);
  long a_src[AI];
  #pragma unroll
  for (int j=0;j<AI;j++){
    int li = (w*AI+j)*8 + (lane>>3);
    int row;
    if constexpr (MODE == 0){
      row = loc0 + li;
    } else {
      int ll = loc0 + li; if (ll > cnt-1) ll = cnt-1;
      if constexpr (MODE == 1) row = etok[e*TT + ll];
      else                     row = off0 + ll;
    }
    a_src[j] = (long)row*Kfull + kbase + c16*8;
  }
  long b_src[BI];
  #pragma unroll
  for (int j=0;j<BI;j++){
    int rr = bx*BN + (w*BI+j)*8 + (lane>>3);
    b_src[j] = (long)rr*Kfull + kbase + c16*8;
  }

  auto STAGE = [&](u16 (&Ad)[BM*64], u16 (&Bd)[BN*64], int t){
    #pragma unroll
    for (int j=0;j<AI;j++)
      __builtin_amdgcn_global_load_lds(
        (const __attribute__((address_space(1))) void*)(A + a_src[j] + t*64),
        (__attribute__((address_space(3))) void*)(&Ad[(w*AI+j)*512]), 16, 0, 0);
    #pragma unroll
    for (int j=0;j<BI;j++)
      __builtin_amdgcn_global_load_lds(
        (const __attribute__((address_space(1))) void*)(Wz + b_src[j] + t*64),
        (__attribute__((address_space(3))) void*)(&Bd[(w*BI+j)*512]), 16, 0, 0);
  };

  f32x4 acc[FM][FN];
  #pragma unroll
  for (int m=0;m<FM;m++)
    #pragma unroll
    for (int n=0;n<FN;n++) acc[m][n] = (f32x4){0.f,0.f,0.f,0.f};

  const int lr = lane & 15;
  const int s0 = (lane>>4) ^ (lane&7);
  const int abase = lr*128 + s0*16;

  auto COMP = [&](const u16 (&As)[BM*64], const u16 (&Bs)[BN*64]){
    const char* Ab = (const char*)&As[0];
    const char* Bb = (const char*)&Bs[0];
    bf16x8 af[FM][2], bfr[FN][2];
    #pragma unroll
    for (int m=0;m<FM;m++){
      af[m][0] = *reinterpret_cast<const bf16x8*>(Ab + wm*(BM/2)*128 + m*2048 + abase);
      af[m][1] = *reinterpret_cast<const bf16x8*>(Ab + wm*(BM/2)*128 + m*2048 + (abase^64));
    }
    #pragma unroll
    for (int n=0;n<FN;n++){
      bfr[n][0] = *reinterpret_cast<const bf16x8*>(Bb + wn*(BN/4)*128 + n*2048 + abase);
      bfr[n][1] = *reinterpret_cast<const bf16x8*>(Bb + wn*(BN/4)*128 + n*2048 + (abase^64));
    }
    #pragma unroll
    for (int m=0;m<FM;m++)
      #pragma unroll
      for (int n=0;n<FN;n++){
        acc[m][n] = __builtin_amdgcn_mfma_f32_16x16x32_bf16(af[m][0], bfr[n][0], acc[m][n], 0,0,0);
        acc[m][n] = __builtin_amdgcn_mfma_f32_16x16x32_bf16(af[m][1], bfr[n][1], acc[m][n], 0,0,0);
      }
  };

  const int nt = Kchunk >> 6;
  STAGE(As0, Bs0, 0);
  __syncthreads();
  for (int t=0; t<nt; t+=2){
    if (t+1 < nt) STAGE(As1, Bs1, t+1);
    COMP(As0, Bs0);
    __syncthreads();
    if (t+1 < nt){
      if (t+2 < nt) STAGE(As0, Bs0, t+2);
      COMP(As1, Bs1);
      __syncthreads();
    }
  }

  const float* bz = (bias && kc==0) ? (bias + (long)e*biasStride) : nullptr;
  #pragma unroll
  for (int m=0;m<FM;m++){
    #pragma unroll
    for (int n=0;n<FN;n++){
      int gcol = bx*BN + wn*(BN/4) + n*16 + (lane&15);
      float bv = bz ? bz[gcol] : 0.f;
      #pragma unroll
      for (int jj=0;jj<4;jj++){
        int li = wm*(BM/2) + m*16 + (lane>>4)*4 + jj;
        int ll = loc0 + li;
        if (MODE != 0 && ll >= cnt) continue;
        float v = acc[m][n][jj] + bv;
        if constexpr (EPI == 3) v = gelu_tanh(v);
        long orow = (MODE == 0) ? (long)ll : (long)(off0 + ll);
        ((__hip_bfloat16*)Cout)[kc*sCk + orow*ldc + gcol] = __float2bfloat16(v);
      }
    }
  }
}

// ---------------------------------------------------------------------------
// 4-wave GEMM (scores / PV / proj), static double buffers.
// EPI: 0=store f32, 1=store bf16, 2=resadd x += v*scalevec (non-atomic RMW)
// ---------------------------------------------------------------------------
template<int BM,int BN,int EPI>
__global__ __launch_bounds__(256) void gemm_bt(
    const u16* __restrict__ A, const u16* __restrict__ Wb, void* __restrict__ Cout,
    const float* __restrict__ bias, const float* __restrict__ scalevec,
    int M, int Kfull, int nby, int ldc,
    long sA, long sW, long sCo, long sCi, int Z2)
{
  constexpr int FM = BM/32, FN = BN/32;
  constexpr int AI = BM/32, BI = BN/32;

  const int ze = blockIdx.z;
  const int nwg = gridDim.x;
  int lin = blockIdx.x;
  int q = nwg >> 3, r = nwg & 7;
  int xcd = lin & 7, pos = lin >> 3;
  int swz = (xcd < r ? xcd*(q+1) : r*(q+1) + (xcd-r)*q) + pos;
  const int bx = swz / nby;
  const int by = swz - bx*nby;
  if (by*BM >= M) return;

  const int tid = threadIdx.x, w = tid>>6, lane = tid&63;
  const int wm = w>>1, wn = w&1;

  __shared__ __align__(16) u16 As0[BM*64], As1[BM*64];
  __shared__ __align__(16) u16 Bs0[BN*64], Bs1[BN*64];

  const u16* Az = A + (long)ze*sA;
  const u16* Wz = Wb + (long)ze*sW;

  const int c16 = (lane&7) ^ ((lane>>3)&7);
  long a_src[AI];
  #pragma unroll
  for (int j=0;j<AI;j++){
    int i = by*BM + (w*AI+j)*8 + (lane>>3);
    a_src[j] = (long)i*Kfull + c16*8;
  }
  long b_src[BI];
  #pragma unroll
  for (int j=0;j<BI;j++){
    int rr = bx*BN + (w*BI+j)*8 + (lane>>3);
    b_src[j] = (long)rr*Kfull + c16*8;
  }

  auto STAGE = [&](u16 (&Ad)[BM*64], u16 (&Bd)[BN*64], int t){
    #pragma unroll
    for (int j=0;j<AI;j++)
      __builtin_amdgcn_global_load_lds(
        (const __attribute__((address_space(1))) void*)(Az + a_src[j] + t*64),
        (__attribute__((address_space(3))) void*)(&Ad[(w*AI+j)*512]), 16, 0, 0);
    #pragma unroll
    for (int j=0;j<BI;j++)
      __builtin_amdgcn_global_load_lds(
        (const __attribute__((address_space(1))) void*)(Wz + b_src[j] + t*64),
        (__attribute__((address_space(3))) void*)(&Bd[(w*BI+j)*512]), 16, 0, 0);
  };

  f32x4 acc[FM][FN];
  #pragma unroll
  for (int m=0;m<FM;m++)
    #pragma unroll
    for (int n=0;n<FN;n++) acc[m][n] = (f32x4){0.f,0.f,0.f,0.f};

  const int lr = lane & 15;
  const int s0 = (lane>>4) ^ (lane&7);
  const int abase = lr*128 + s0*16;

  auto COMP = [&](const u16 (&As)[BM*64], const u16 (&Bs)[BN*64]){
    const char* Ab = (const char*)&As[0];
    const char* Bb = (const char*)&Bs[0];
    bf16x8 af[FM][2], bfr[FN][2];
    #pragma unroll
    for (int m=0;m<FM;m++){
      af[m][0] = *reinterpret_cast<const bf16x8*>(Ab + wm*(BM/2)*128 + m*2048 + abase);
      af[m][1] = *reinterpret_cast<const bf16x8*>(Ab + wm*(BM/2)*128 + m*2048 + (abase^64));
    }
    #pragma unroll
    for (int n=0;n<FN;n++){
      bfr[n][0] = *reinterpret_cast<const bf16x8*>(Bb + wn*(BN/2)*128 + n*2048 + abase);
      bfr[n][1] = *reinterpret_cast<const bf16x8*>(Bb + wn*(BN/2)*128 + n*2048 + (abase^64));
    }
    #pragma unroll
    for (int m=0;m<FM;m++)
      #pragma unroll
      for (int n=0;n<FN;n++){
        acc[m][n] = __builtin_amdgcn_mfma_f32_16x16x32_bf16(af[m][0], bfr[n][0], acc[m][n], 0,0,0);
        acc[m][n] = __builtin_amdgcn_mfma_f32_16x16x32_bf16(af[m][1], bfr[n][1], acc[m][n], 0,0,0);
      }
  };

  const int nt = Kfull >> 6;
  STAGE(As0, Bs0, 0);
  __syncthreads();
  for (int t=0; t<nt; t+=2){
    if (t+1 < nt) STAGE(As1, Bs1, t+1);
    COMP(As0, Bs0);
    __syncthreads();
    if (t+1 < nt){
      if (t+2 < nt) STAGE(As0, Bs0, t+2);
      COMP(As1, Bs1);
      __syncthreads();
    }
  }

  long csel = (long)(ze/Z2)*sCo + (long)(ze%Z2)*sCi;
  #pragma unroll
  for (int m=0;m<FM;m++){
    #pragma unroll
    for (int n=0;n<FN;n++){
      int gcol = bx*BN + wn*(BN/2) + n*16 + (lane&15);
      float bv = bias ? bias[gcol] : 0.f;
      #pragma unroll
      for (int jj=0;jj<4;jj++){
        int i = by*BM + wm*(BM/2) + m*16 + (lane>>4)*4 + jj;
        float v = acc[m][n][jj] + bv;
        if constexpr (EPI == 0){
          ((float*)Cout)[csel + (long)i*ldc + gcol] = v;
        } else if constexpr (EPI == 1){
          ((__hip_bfloat16*)Cout)[csel + (long)i*ldc + gcol] = __float2bfloat16(v);
        } else {
          float* p = (float*)Cout + csel + (long)i*ldc + gcol;
          *p += v * scalevec[gcol];
        }
      }
    }
  }
}

// ---------------------------------------------------------------------------
__global__ __launch_bounds__(256) void cvt_kernel(const float* __restrict__ s,
    u16* __restrict__ d, long n)
{
  long i = ((long)blockIdx.x*256 + threadIdx.x)*8;
  if (i >= n) return;
  float4 a = *(const float4*)(s+i);
  float4 b = *(const float4*)(s+i+4);
  union { __hip_bfloat162 h[4]; uint4 v; } o;
  o.h[0] = __float22bfloat162_rn(make_float2(a.x,a.y));
  o.h[1] = __float22bfloat162_rn(make_float2(a.z,a.w));
  o.h[2] = __float22bfloat162_rn(make_float2(b.x,b.y));
  o.h[3] = __float22bfloat162_rn(make_float2(b.z,b.w));
  *(uint4*)(d+i) = o.v;
}

__global__ __launch_bounds__(256) void init_x_kernel(const float* __restrict__ h,
    float* __restrict__ x, int n)
{
  int i = blockIdx.x*256 + threadIdx.x;
  if (i < n) x[i] = h[i];
  else if (i == n) x[i] = 0.f;   // aux slot
}

__global__ __launch_bounds__(256) void ln_kernel(const float* __restrict__ x,
    const float* __restrict__ s, const float* __restrict__ b,
    float* __restrict__ of, __hip_bfloat16* __restrict__ ob)
{
  int row = blockIdx.x, tid = threadIdx.x;
  const float* xr = x + (long)row*TC;
  int c = tid*4;
  float4 xv = *(const float4*)(xr + c);
  float sum = xv.x+xv.y+xv.z+xv.w;
  float sq = xv.x*xv.x+xv.y*xv.y+xv.z*xv.z+xv.w*xv.w;
  #pragma unroll
  for (int o=32;o;o>>=1){ sum += __shfl_down(sum,o); sq += __shfl_down(sq,o); }
  __shared__ float ls[8];
  if ((tid&63)==0){ ls[tid>>6] = sum; ls[4+(tid>>6)] = sq; }
  __syncthreads();
  float mean = (ls[0]+ls[1]+ls[2]+ls[3]) * (1.f/TC);
  float ex2  = (ls[4]+ls[5]+ls[6]+ls[7]) * (1.f/TC);
  float rstd = rsqrtf(ex2 - mean*mean + 1e-6f);
  float4 sv = *(const float4*)(s + c);
  float4 bv = *(const float4*)(b + c);
  float o0 = (xv.x-mean)*rstd*sv.x + bv.x;
  float o1 = (xv.y-mean)*rstd*sv.y + bv.y;
  float o2 = (xv.z-mean)*rstd*sv.z + bv.z;
  float o3 = (xv.w-mean)*rstd*sv.w + bv.w;
  *(float4*)(of + (long)row*TC + c) = make_float4(o0,o1,o2,o3);
  __hip_bfloat16* op = ob + (long)row*TC + c;
  *reinterpret_cast<__hip_bfloat162*>(op)   = __float22bfloat162_rn(make_float2(o0,o1));
  *reinterpret_cast<__hip_bfloat162*>(op+2) = __float22bfloat162_rn(make_float2(o2,o3));
}

__global__ void build_qkv_bias(const float* __restrict__ qb, const float* __restrict__ vb,
    float* __restrict__ out)
{
  int i = blockIdx.x*256 + threadIdx.x;
  if (i >= 3*TC) return;
  float v = 0.f;
  if (i < TC) v = qb[i];
  else if (i >= 2*TC) v = vb[i-2*TC];
  out[i] = v;
}

// grid (TN/128, TBH): copy q,k sections; LDS-transpose v into vT[bh][d][n]
__global__ __launch_bounds__(256) void qkv_reshape(const u16* __restrict__ qkv,
    u16* __restrict__ q, u16* __restrict__ k, u16* __restrict__ vT)
{
  const int bh = blockIdx.y, b = bh>>4, h = bh&15;
  const int n0 = blockIdx.x*128;
  const int tid = threadIdx.x;
  const long rowbase = ((long)b*TN + n0)*(3*TC) + h*THD;
  __shared__ u16 vt[128][72];
  #pragma unroll
  for (int j=0;j<4;j++){
    int f = j*2048 + tid*8;
    int r = f>>6, d = f&63;
    long src = rowbase + (long)r*(3*TC) + d;
    long dst = ((long)bh*TN + n0 + r)*THD + d;
    *(uint4*)(q + dst) = *(const uint4*)(qkv + src);
    *(uint4*)(k + dst) = *(const uint4*)(qkv + src + TC);
    *(uint4*)(&vt[r][d]) = *(const uint4*)(qkv + src + 2*TC);
  }
  __syncthreads();
  #pragma unroll
  for (int j=0;j<4;j++){
    int f = j*2048 + tid*8;
    int dr = f>>7, nc = f&127;
    union { uint4 v; u16 u[8]; } o;
    #pragma unroll
    for (int e=0;e<8;e++) o.u[e] = vt[nc+e][dr];
    *(uint4*)(vT + ((long)bh*THD + dr)*TN + n0 + nc) = o.v;
  }
}

__global__ __launch_bounds__(256) void softmax_kernel(const float* __restrict__ S,
    const float* __restrict__ rpb, const int* __restrict__ mask, __hip_bfloat16* __restrict__ P)
{
  int row = blockIdx.x, tid = threadIdx.x;
  int qpos = row % TN;
  int bh = row / TN;
  int h = bh & (TH-1);
  int b = bh >> 4;
  const float* srow = S + (long)row*TN;
  const float* rrow = rpb + ((long)h*TN + qpos)*TN;
  const int* mrow = mask + b*TN;
  float v[3];
  float mx = -3e38f;
  #pragma unroll
  for (int j=0;j<3;j++){
    int kk = tid + j*256;
    float t = -3e38f;
    if (kk < TN){
      t = srow[kk]*SCALE_ + rrow[kk];
      if (mrow[kk] == 0) t = -1e30f;
    }
    v[j] = t;
    mx = fmaxf(mx, t);
  }
  #pragma unroll
  for (int o=32;o;o>>=1) mx = fmaxf(mx, __shfl_down(mx,o));
  __shared__ float ls[4], ls2[4];
  if ((tid&63)==0) ls[tid>>6] = mx;
  __syncthreads();
  mx = fmaxf(fmaxf(ls[0],ls[1]), fmaxf(ls[2],ls[3]));
  float sum = 0.f;
  #pragma unroll
  for (int j=0;j<3;j++){
    int kk = tid + j*256;
    if (kk < TN){ v[j] = __expf(v[j]-mx); sum += v[j]; }
  }
  #pragma unroll
  for (int o=32;o;o>>=1) sum += __shfl_down(sum,o);
  if ((tid&63)==0) ls2[tid>>6] = sum;
  __syncthreads();
  float inv = 1.f/(ls2[0]+ls2[1]+ls2[2]+ls2[3]);
  #pragma unroll
  for (int j=0;j<3;j++){
    int kk = tid + j*256;
    if (kk < TN) P[(long)row*TN + kk] = __float2bfloat16(v[j]*inv);
  }
}

__global__ __launch_bounds__(256) void gate_kernel(const float* __restrict__ ln,
    const float* __restrict__ gw, float* __restrict__ logits)
{
  int t = blockIdx.x, tid = threadIdx.x;
  int c = tid*4;
  float4 xv = *(const float4*)(ln + (long)t*TC + c);
  __shared__ float ls[4];
  for (int e=0;e<TE;e++){
    float4 wv = *(const float4*)(gw + (long)e*TC + c);
    float p = xv.x*wv.x + xv.y*wv.y + xv.z*wv.z + xv.w*wv.w;
    #pragma unroll
    for (int o=32;o;o>>=1) p += __shfl_down(p,o);
    if ((tid&63)==0) ls[tid>>6] = p;
    __syncthreads();
    if (tid==0) logits[(long)t*TE + e] = ls[0]+ls[1]+ls[2]+ls[3];
    __syncthreads();
  }
}

__global__ __launch_bounds__(256) void routing_kernel(const float* __restrict__ logits,
    int* __restrict__ counts, int* __restrict__ etok,
    int* __restrict__ tEt, int* __restrict__ tPt, float* __restrict__ tGt,
    float* __restrict__ psum)
{
  __shared__ float ps[TE];
  int tid = threadIdx.x;
  if (tid < TE) ps[tid] = 0.f;
  __syncthreads();
  int t = blockIdx.x*256 + tid;
  if (t < TT){
    float pr[TE]; float mx = -3e38f;
    #pragma unroll
    for (int e=0;e<TE;e++){ pr[e] = logits[(long)t*TE+e]; mx = fmaxf(mx, pr[e]); }
    float sum = 0.f;
    #pragma unroll
    for (int e=0;e<TE;e++){ pr[e] = __expf(pr[e]-mx); sum += pr[e]; }
    float inv = 1.f/sum;
    #pragma unroll
    for (int e=0;e<TE;e++) pr[e] *= inv;
    int i1 = 0;
    #pragma unroll
    for (int e=1;e<TE;e++) if (pr[e] > pr[i1]) i1 = e;
    int i2 = -1;
    #pragma unroll
    for (int e=0;e<TE;e++){ if (e==i1) continue; if (i2<0 || pr[e]>pr[i2]) i2=e; }
    float p1 = pr[i1], p2 = pr[i2];
    float g1 = p1/(p1+p2), g2 = p2/(p1+p2);
    int pos1 = atomicAdd(&counts[i1], 1);
    etok[i1*TT + pos1] = t;
    int pos2 = atomicAdd(&counts[i2], 1);
    etok[i2*TT + pos2] = t;
    tEt[2*t] = i1; tPt[2*t] = pos1; tGt[2*t] = g1;
    tEt[2*t+1] = i2; tPt[2*t+1] = pos2; tGt[2*t+1] = g2;
    #pragma unroll
    for (int e=0;e<TE;e++) atomicAdd(&ps[e], pr[e]);
  }
  __syncthreads();
  if (tid < TE) atomicAdd(&psum[tid], ps[tid]);
}

__global__ void finalize_routing(const int* __restrict__ counts, int* __restrict__ offsets,
    const float* __restrict__ psum, float* __restrict__ aux,
    int* __restrict__ tE1, int* __restrict__ tL1, int* __restrict__ tC1, int* __restrict__ tO1,
    int* __restrict__ tE2, int* __restrict__ tL2, int* __restrict__ tC2, int* __restrict__ tO2)
{
  int off = 0; float a = 0.f; int n1 = 0, n2 = 0;
  for (int e=0;e<TE;e++){
    offsets[e] = off; int c = counts[e];
    for (int j=0;j<c;j+=256){ tE1[n1]=e; tL1[n1]=j; tC1[n1]=c; tO1[n1]=off; n1++; }
    for (int j=0;j<c;j+=128){ tE2[n2]=e; tL2[n2]=j; tC2[n2]=c; tO2[n2]=off; n2++; }
    a += (psum[e]*(1.f/TT)) * ((float)c*(1.f/TT));
    off += c;
  }
  for (;n1<NT1;n1++) tE1[n1] = -1;
  for (;n2<NT2;n2++) tE2[n2] = -1;
  aux[0] += (float)TE * a;
}

// x[t] += (g1*(y0+y1)[s1] + g2*(y0+y1)[s2]) * gamma2
__global__ __launch_bounds__(256) void combine_kernel(
    const u16* __restrict__ y, long yck, const int* __restrict__ tEt,
    const int* __restrict__ tPt, const float* __restrict__ tGt,
    const int* __restrict__ offsets, const float* __restrict__ gamma2,
    float* __restrict__ x)
{
  int t = blockIdx.x, c = threadIdx.x*4;
  int e1 = tEt[2*t], e2 = tEt[2*t+1];
  long s1 = (long)(offsets[e1]+tPt[2*t])*TC + c;
  long s2 = (long)(offsets[e2]+tPt[2*t+1])*TC + c;
  float g1 = tGt[2*t], g2 = tGt[2*t+1];
  ushort4 a0 = *(const ushort4*)(y+s1);
  ushort4 a1 = *(const ushort4*)(y+yck+s1);
  ushort4 b0 = *(const ushort4*)(y+s2);
  ushort4 b1 = *(const ushort4*)(y+yck+s2);
  float4 gv = *(const float4*)(gamma2 + c);
  float* xp = x + (long)t*TC + c;
  float4 xv = *(const float4*)xp;
  auto f = [](u16 u){ union{float f;unsigned i;} v; v.i = (unsigned)u<<16; return v.f; };
  xv.x += (g1*(f(a0.x)+f(a1.x)) + g2*(f(b0.x)+f(b1.x)))*gv.x;
  xv.y += (g1*(f(a0.y)+f(a1.y)) + g2*(f(b0.y)+f(b1.y)))*gv.y;
  xv.z += (g1*(f(a0.z)+f(a1.z)) + g2*(f(b0.z)+f(b1.z)))*gv.z;
  xv.w += (g1*(f(a0.w)+f(a1.w)) + g2*(f(b0.w)+f(b1.w)))*gv.w;
  *(float4*)xp = xv;
}

// ---------------------------------------------------------------------------
extern "C" void kernel_launch(void* const* d_in, const int* in_sizes, int n_in,
                              void* d_out, int out_size, void* d_ws, size_t ws_size,
                              hipStream_t stream) {
  (void)in_sizes; (void)n_in; (void)out_size; (void)ws_size;
  const float* hidden = (const float*)d_in[0];
  const int*   amask  = (const int*)d_in[1];
  const float* rpb    = (const float*)d_in[2];
  const float* qkv_w  = (const float*)d_in[3];
  const float* q_bias = (const float*)d_in[4];
  const float* v_bias = (const float*)d_in[5];
  const float* proj_w = (const float*)d_in[6];
  const float* proj_b = (const float*)d_in[7];
  const float* ln1_s  = (const float*)d_in[8];
  const float* ln1_b  = (const float*)d_in[9];
  const float* ln2_s  = (const float*)d_in[10];
  const float* ln2_b  = (const float*)d_in[11];
  const float* gamma1 = (const float*)d_in[12];
  const float* gamma2 = (const float*)d_in[13];
  const float* gate_w = (const float*)d_in[14];
  const float* fc1_w  = (const float*)d_in[15];
  const float* fc1_b  = (const float*)d_in[16];
  const float* fc2_w  = (const float*)d_in[17];
  const float* fc2_b  = (const float*)d_in[18];

  float* x = (float*)d_out;
  const int NXC = TT*TC;

  char* p = (char*)d_ws;
  auto alloc = [&](size_t bytes)->void* {
    void* r = (void*)p; p += (bytes + 255) & ~(size_t)255; return r;
  };
  float* qkvbias = (float*)alloc(3*TC*4);
  u16*   ln_bf   = (u16*)alloc((size_t)TT*TC*2);
  float* ln_f    = (float*)alloc((size_t)TT*TC*4);
  float* logits  = (float*)alloc((size_t)TT*TE*4);
  int*   counts  = (int*)alloc(TE*4);
  int*   offsets = (int*)alloc(TE*4);
  float* psum    = (float*)alloc(TE*4);
  int*   etok    = (int*)alloc((size_t)TE*TT*4);
  int*   tEt     = (int*)alloc((size_t)2*TT*4);
  int*   tPt     = (int*)alloc((size_t)2*TT*4);
  float* tGt     = (float*)alloc((size_t)2*TT*4);
  int*   tE1 = (int*)alloc(NT1*4); int* tL1 = (int*)alloc(NT1*4);
  int*   tC1 = (int*)alloc(NT1*4); int* tO1 = (int*)alloc(NT1*4);
  int*   tE2 = (int*)alloc(NT2*4); int* tL2 = (int*)alloc(NT2*4);
  int*   tC2 = (int*)alloc(NT2*4); int* tO2 = (int*)alloc(NT2*4);
  char* arena = (char*)alloc(202375168);
  // attention phase
  float* scores  = (float*)(arena);                         // 104,857,600
  u16*   Pb      = (u16*)(arena + 104857600);               //  52,428,800
  u16*   qkv_bf  = (u16*)(arena + 157286400);               //  15,728,640
  u16*   qb      = (u16*)(arena + 173015040);               //   5,242,880
  u16*   kb      = (u16*)(arena + 178257920);               //   5,242,880
  u16*   vT      = (u16*)(arena + 183500800);               //   5,242,880
  u16*   attn_o  = (u16*)(arena + 188743680);               //   5,242,880
  u16*   wqkv    = (u16*)(arena + 193986560);               //   6,291,456
  u16*   wproj   = (u16*)(arena + 200278016);               //   2,097,152
  // MoE phase (overlays attention-phase buffers — dead by then)
  u16*   fc1b    = (u16*)(arena);                           //  67,108,864
  u16*   fc2b    = (u16*)(arena + 67108864);                //  67,108,864
  u16*   h1      = (u16*)(arena + 134217728);               //  41,943,040 (5120 x TI bf16)
  u16*   yslot   = (u16*)(arena + 176160768);               //  20,971,520 (2 x 5120 x TC bf16)
  const long YCK = (long)5120*TC;

  init_x_kernel<<<(NXC+1+255)/256, 256, 0, stream>>>(hidden, x, NXC);

  for (int l=0;l<2;l++){
    // --- attention ---
    ln_kernel<<<TT, 256, 0, stream>>>(x, ln1_s + l*TC, ln1_b + l*TC, ln_f, (__hip_bfloat16*)ln_bf);
    build_qkv_bias<<<(3*TC+255)/256, 256, 0, stream>>>(q_bias + l*TC, v_bias + l*TC, qkvbias);
    cvt_kernel<<<(3*TC*TC)/2048, 256, 0, stream>>>(qkv_w + (size_t)l*3*TC*TC, wqkv, (long)3*TC*TC);
    cvt_kernel<<<(TC*TC)/2048, 256, 0, stream>>>(proj_w + (size_t)l*TC*TC, wproj, (long)TC*TC);
    gemm8<256,128,0,1><<<dim3(240,1,1), 512, 0, stream>>>(
        ln_bf, wqkv, qkv_bf, qkvbias, 0,
        nullptr, nullptr, nullptr, nullptr, nullptr,
        TT, TC, TC, 10, 3*TC, 0, 0);
    qkv_reshape<<<dim3(TN/128, TBH), 256, 0, stream>>>(qkv_bf, qb, kb, vT);
    gemm_bt<128,128,0><<<dim3(5*5,1,TBH), 256, 0, stream>>>(
        qb, kb, scores, nullptr, nullptr,
        TN, THD, 5, TN, (long)TN*THD, (long)TN*THD, (long)TN*TN, 0, 1);
    softmax_kernel<<<TBH*TN, 256, 0, stream>>>(scores, rpb, amask, (__hip_bfloat16*)Pb);
    cvt_kernel<<<(TE*TI*TC)/2048, 256, 0, stream>>>(fc1_w + (size_t)l*TE*TI*TC, fc1b, (long)TE*TI*TC);
    gemm_bt<128,64,1><<<dim3(1*5,1,TBH), 256, 0, stream>>>(
        Pb, vT, attn_o, nullptr, nullptr,
        TN, TN, 5, TC, (long)TN*TN, (long)THD*TN, (long)TN*TC, THD, TH);
    cvt_kernel<<<(TE*TC*TI)/2048, 256, 0, stream>>>(fc2_w + (size_t)l*TE*TC*TI, fc2b, (long)TE*TC*TI);
    gemm_bt<64,128,2><<<dim3(8*40,1,1), 256, 0, stream>>>(
        attn_o, wproj, x, proj_b + l*TC, gamma1 + l*TC,
        TT, TC, 40, TC, 0,0,0,0,1);

    // --- MoE ---
    ln_kernel<<<TT, 256, 0, stream>>>(x, ln2_s + l*TC, ln2_b + l*TC, ln_f, (__hip_bfloat16*)ln_bf);
    gate_kernel<<<TT, 256, 0, stream>>>(ln_f, gate_w + (size_t)l*TE*TC, logits);
    hipMemsetAsync(counts, 0, TE*4, stream);
    hipMemsetAsync(psum, 0, TE*4, stream);
    routing_kernel<<<(TT+255)/256, 256, 0, stream>>>(logits, counts, etok, tEt, tPt, tGt, psum);
    finalize_routing<<<1, 1, 0, stream>>>(counts, offsets, psum, x + NXC,
        tE1, tL1, tC1, tO1, tE2, tL2, tC2, tO2);
    // fc1: 256x256 tiles, gather, gelu
    gemm8<256,256,1,3><<<dim3(16*NT1,1,1), 512, 0, stream>>>(
        ln_bf, fc1b, h1, fc1_b + (size_t)l*TE*TI, TI,
        tE1, tL1, tC1, tO1, etok,
        0, TC, TC, 16, TI, (long)TI*TC, 0);
    // fc2: 128x256 tiles, compact rows, split-K=2, bf16 partials
    gemm8<128,256,2,1><<<dim3(4*NT2,1,2), 512, 0, stream>>>(
        h1, fc2b, yslot, fc2_b + (size_t)l*TE*TC, TC,
        tE2, tL2, tC2, tO2, nullptr,
        0, TI, TI/2, 4, TC, (long)TC*TI, YCK);
    combine_kernel<<<TT, 256, 0, stream>>>(yslot, YCK, tEt, tPt, tGt, offsets, gamma2 + l*TC, x);
  }
}